// Round 5
// baseline (283.585 us; speedup 1.0000x reference)
//
#include <hip/hip_runtime.h>
#include <hip/hip_bf16.h>
#include <math.h>

typedef __bf16 bf16_t;
typedef __bf16 bf16x4 __attribute__((ext_vector_type(4)));
typedef __bf16 bf16x8 __attribute__((ext_vector_type(8)));
typedef float f32x4 __attribute__((ext_vector_type(4)));

#define LOG2E 1.44269504088896340736f

// async global->LDS DMA, 16B per lane; LDS dest = wave-uniform base + lane*16
#define GL2LDS(g, l)                                                     \
  __builtin_amdgcn_global_load_lds(                                      \
      (const __attribute__((address_space(1))) unsigned int*)(g),        \
      (__attribute__((address_space(3))) unsigned int*)(l), 16, 0, 0)

// raw barrier with compiler memory fence (NO implicit vmcnt drain)
#define BAR() asm volatile("s_barrier" ::: "memory")
#define VMCNT(n) asm volatile("s_waitcnt vmcnt(" #n ")" ::: "memory")
#define LGKM0()                                         \
  do {                                                  \
    asm volatile("s_waitcnt lgkmcnt(0)" ::: "memory");  \
    __builtin_amdgcn_sched_barrier(0);                  \
  } while (0)

// ------------- convert f32 -> bf16, 8 elems/thread ------------------------
__global__ __launch_bounds__(256) void convert_f32_bf16(const float* __restrict__ in,
                                                        bf16_t* __restrict__ out) {
  const size_t idx = (size_t)(blockIdx.x * 256 + threadIdx.x) * 8;
  f32x4 a = *(const f32x4*)&in[idx];
  f32x4 b = *(const f32x4*)&in[idx + 4];
  bf16x8 v;
#pragma unroll
  for (int i = 0; i < 4; i++) { v[i] = (bf16_t)a[i]; v[i + 4] = (bf16_t)b[i]; }
  *(bf16x8*)&out[idx] = v;
}

// ------------- transpose+convert: in f32 [R][C] -> out bf16 [C][R] --------
__global__ __launch_bounds__(256) void transpose_f32_bf16(const float* __restrict__ in,
                                                          bf16_t* __restrict__ out,
                                                          int R, int C) {
  __shared__ bf16_t t[64][65];
  const int c0 = blockIdx.x * 64, r0 = blockIdx.y * 64;
  const int tx = threadIdx.x, ty = threadIdx.y;  // 64 x 4
#pragma unroll
  for (int i = 0; i < 16; i++) {
    int r = ty + i * 4;
    t[r][tx] = (bf16_t)in[(size_t)(r0 + r) * C + c0 + tx];
  }
  __syncthreads();
#pragma unroll
  for (int i = 0; i < 16; i++) {
    int r = ty + i * 4;
    out[(size_t)(c0 + r) * R + r0 + tx] = t[tx][r];
  }
}

// ---- 128x128 MFMA GEMM, BK=32, TRIPLE-buffered, counted vmcnt(4) ---------
// (round-4 best: 95 us gemm0, FETCH 57.6MB w/ XCD swizzle, 0 conflicts)
// Prefetch distance 2: at tile t stage tile t+2 into buf[(t+2)%3]; the
// end-of-tile VMCNT(4) waits only for group t+1 (issued one full tile ago)
// and leaves group t+2 in flight (T4). 256 thr = 4 waves (2x2), wave tile
// 64x64, LDS 48KB -> 3 blocks/CU.
// Swizzle (verified zero-conflict): LDS chunk (r,p) holds global chunk
// p ^ ((r>>1)&3); frag read at chunk lq ^ ((row>>1)&3) -> free 2-way.
// MODE 0: epilogue scatters qkv into Q(pre-scaled)/K [B][H][N][64], Vt [B][H][64][N]
// MODE 1: epilogue adds f32 bias, writes f32 [M][1024]
template <int MODE>
__global__ __launch_bounds__(256, 4) void gemmT(const bf16_t* __restrict__ A,
                                                const bf16_t* __restrict__ Bt,
                                                bf16_t* __restrict__ Qb,
                                                bf16_t* __restrict__ Kb,
                                                bf16_t* __restrict__ Vtb,
                                                const float* __restrict__ bias,
                                                float* __restrict__ Out) {
  constexpr int K = 1024;
  constexpr int NT = K / 32;  // 32 K-tiles
  __shared__ __align__(16) bf16_t As[3][128 * 32];
  __shared__ __align__(16) bf16_t Bs[3][128 * 32];
  // XCD-aware bijective swizzle (grid sizes are multiples of 8)
  const int gx = gridDim.x;
  const int lin = blockIdx.y * gx + blockIdx.x;
  const int per = (gx * gridDim.y) >> 3;
  const int swz = (lin & 7) * per + (lin >> 3);
  const int m0 = (swz / gx) * 128, n0 = (swz % gx) * 128;
  const int tid = threadIdx.x;
  const int w = tid >> 6, l = tid & 63;
  const int lr = l & 15, lq = l >> 4;
  const int wm = w >> 1, wn = w & 1;  // 2 x 2 wave grid, wave tile 64x64

  // staging: chunk c = slot*256 + tid; r = c>>2 = slot*64 + (tid>>2),
  // LDS pos p = c&3, source chunk = p ^ ((r>>1)&3) (slot-invariant)
  const int rs = tid >> 2, ps = tid & 3;
  const int cs = (ps ^ ((rs >> 1) & 3)) * 8;
  const size_t gA0 = (size_t)(m0 + rs) * K + cs;
  const size_t gA1 = (size_t)(m0 + 64 + rs) * K + cs;
  const size_t gB0 = (size_t)(n0 + rs) * K + cs;
  const size_t gB1 = (size_t)(n0 + 64 + rs) * K + cs;
  const int ldsu0 = (w * 64) * 8;          // wave-uniform LDS elem offsets
  const int ldsu1 = (256 + w * 64) * 8;

#define STG(bf_, kt_)                                   \
  do {                                                  \
    const size_t kk_ = (size_t)(kt_) * 32;              \
    GL2LDS(&A[gA0 + kk_], &As[bf_][ldsu0]);             \
    GL2LDS(&A[gA1 + kk_], &As[bf_][ldsu1]);             \
    GL2LDS(&Bt[gB0 + kk_], &Bs[bf_][ldsu0]);            \
    GL2LDS(&Bt[gB1 + kk_], &Bs[bf_][ldsu1]);            \
  } while (0)

  // frag ds_read offsets (elems); row*64B base + swizzled 16B chunk
  int aoff[4], boff[4];
#pragma unroll
  for (int mf = 0; mf < 4; mf++) {
    const int row = wm * 64 + mf * 16 + lr;
    aoff[mf] = row * 32 + ((lq ^ ((row >> 1) & 3)) << 3);
  }
#pragma unroll
  for (int nf = 0; nf < 4; nf++) {
    const int row = wn * 64 + nf * 16 + lr;
    boff[nf] = row * 32 + ((lq ^ ((row >> 1) & 3)) << 3);
  }

  f32x4 acc[4][4] = {};

  // prologue: stage tiles 0 and 1 (groups of 4 loads each); wait group 0
  STG(0, 0);
  STG(1, 1);
  VMCNT(4);
  BAR();

  for (int t = 0; t < NT; ++t) {
    const int bufR = t % 3;
    if (t + 2 < NT) STG((t + 2) % 3, t + 2);
    bf16x8 af[4], bv[4];
#pragma unroll
    for (int mf = 0; mf < 4; mf++)
      af[mf] = *(const bf16x8*)&As[bufR][aoff[mf]];
#pragma unroll
    for (int nf = 0; nf < 4; nf++)
      bv[nf] = *(const bf16x8*)&Bs[bufR][boff[nf]];
    LGKM0();
    __builtin_amdgcn_s_setprio(1);
#pragma unroll
    for (int mf = 0; mf < 4; mf++)
#pragma unroll
      for (int nf = 0; nf < 4; nf++)
        acc[mf][nf] = __builtin_amdgcn_mfma_f32_16x16x32_bf16(af[mf], bv[nf],
                                                              acc[mf][nf], 0, 0, 0);
    __builtin_amdgcn_s_setprio(0);
    // counted wait: group t+1 must land before the next tile reads it;
    // group t+2 (the 4 newest loads) stays in flight across the barrier.
    if (t == NT - 2) { VMCNT(0); } else if (t < NT - 2) { VMCNT(4); }
    BAR();
  }

#pragma unroll
  for (int mf = 0; mf < 4; mf++)
#pragma unroll
    for (int nf = 0; nf < 4; nf++)
#pragma unroll
      for (int i = 0; i < 4; i++) {
        const int m = m0 + wm * 64 + mf * 16 + lq * 4 + i;  // C/D row=(lane>>4)*4+i
        const int c = n0 + wn * 64 + nf * 16 + lr;          //     col=lane&15
        const float v = acc[mf][nf][i];
        if (MODE == 1) {
          Out[(size_t)m * 1024 + c] = v + bias[c];
        } else {
          const int b = m >> 10, n = m & 1023;
          const int which = c >> 10, cc = c & 1023;
          const int hh = cc >> 6, d = cc & 63;
          const size_t qk = ((size_t)((b * 16 + hh) * 1024 + n)) * 64 + d;
          if (which == 0)
            Qb[qk] = (bf16_t)(v * (0.125f * LOG2E));  // fold softmax scale+log2e
          else if (which == 1)
            Kb[qk] = (bf16_t)v;
          else
            Vtb[((size_t)((b * 16 + hh) * 64 + d)) * 1024 + n] = (bf16_t)v;
        }
      }
}

// ---------------- flash attention v4: operand-swapped, packed P -----------
// 1 block = (b, h, 128-query tile); 4 waves x 32 queries.
// Q pre-scaled by 0.125*log2e -> p = exp2(s).
// v4 changes (theory: 32 scalar ds_write_b16/iter was the port+chain cost):
//  - QK^T computed SWAPPED: sT[nf][mf] = mfma(kf, qf) -> D[n][q]; lane then
//    holds 4 consecutive n per reg -> P store packs to 8x ds_write_b64.
//  - P stored as P[q][n] rows (stride PS=72, 16B chunks XOR-swizzled by
//    (q>>1)&3, same family as the verified GEMM swizzle).
//  - PV computed SWAPPED: o[df][mf] = mfma(vf, pf) -> D[d][q]; pf is a
//    contiguous b128 read of P rows; vf/kf/qf loads unchanged from v3b.
//  - rowsum via all-ones A-frag: o5 = mfma(ones, pf) -> every reg holds
//    rowsum(q=lr) -> inv is lane-local (no __shfl).
//  - bid remapped so the 8 q-tiles of a head share bid%8 (same XCD -> K/V
//    L2 reuse): bid = qt*128 + b*16 + h.
#define KVS 68
#define PS  72
__global__ __launch_bounds__(256) void attn128(const bf16_t* __restrict__ Qb,
                                               const bf16_t* __restrict__ Kb,
                                               const bf16_t* __restrict__ Vtb,
                                               bf16_t* __restrict__ Ob) {
  __shared__ __align__(16) bf16_t Ks[2][64 * KVS];
  __shared__ __align__(16) bf16_t Vs[2][64 * KVS];
  __shared__ __align__(16) bf16_t Pl[4 * 32 * PS];
  const int bid = blockIdx.x;
  const int qt = bid >> 7, b = (bid >> 4) & 7, h = bid & 15;
  const bf16_t* Qh = Qb + (size_t)((b * 16 + h) * 1024) * 64;
  const bf16_t* Kh = Kb + (size_t)((b * 16 + h) * 1024) * 64;
  const bf16_t* Vh = Vtb + (size_t)((b * 16 + h) * 64) * 1024;  // [64][1024] = V^T
  const int tid = threadIdx.x, w = tid >> 6, l = tid & 63;
  const int lr = l & 15, lq = l >> 4;
  const int q0 = qt * 128 + w * 32;
  const int swz = (lr >> 1) & 3;

  bf16x8 onesA;
#pragma unroll
  for (int i = 0; i < 8; i++) onesA[i] = (bf16_t)1.0f;

  const int sr = tid >> 3, sc = tid & 7;

  bf16x8 qf[2][2];
#pragma unroll
  for (int mf = 0; mf < 2; mf++)
#pragma unroll
    for (int ks = 0; ks < 2; ks++)
      qf[mf][ks] = *(const bf16x8*)&Qh[(size_t)(q0 + mf * 16 + lr) * 64 + ks * 32 + lq * 8];

  {  // prologue: stage tile 0
    bf16x8 k0 = *(const bf16x8*)&Kh[(size_t)sr * 64 + sc * 8];
    bf16x8 k1 = *(const bf16x8*)&Kh[(size_t)(sr + 32) * 64 + sc * 8];
    bf16x8 v0 = *(const bf16x8*)&Vh[(size_t)sr * 1024 + sc * 8];
    bf16x8 v1 = *(const bf16x8*)&Vh[(size_t)(sr + 32) * 1024 + sc * 8];
    *(bf16x8*)&Ks[0][sr * KVS + sc * 8] = k0;
    *(bf16x8*)&Ks[0][(sr + 32) * KVS + sc * 8] = k1;
    *(bf16x8*)&Vs[0][sr * KVS + sc * 8] = v0;
    *(bf16x8*)&Vs[0][(sr + 32) * KVS + sc * 8] = v1;
  }
  __syncthreads();

  f32x4 o[4][2] = {};   // [df][mf] O^T frags: rows d, cols q
  f32x4 o5[2] = {};     // rowsum(q) per mf (all regs identical)
  bf16_t* pw = &Pl[w * 32 * PS];

  for (int it = 0; it < 16; ++it) {
    const int buf = it & 1;
    bf16x8 nk0, nk1, nv0, nv1;
    if (it < 15) {
      const int jn = (it + 1) * 64;
      nk0 = *(const bf16x8*)&Kh[(size_t)(jn + sr) * 64 + sc * 8];
      nk1 = *(const bf16x8*)&Kh[(size_t)(jn + sr + 32) * 64 + sc * 8];
      nv0 = *(const bf16x8*)&Vh[(size_t)sr * 1024 + jn + sc * 8];
      nv1 = *(const bf16x8*)&Vh[(size_t)(sr + 32) * 1024 + jn + sc * 8];
    }
    // QK^T, swapped: sT[nf][mf] rows n = nf*16+lq*4+i, cols q = mf*16+lr
    f32x4 s[4][2] = {};
#pragma unroll
    for (int ks = 0; ks < 2; ks++)
#pragma unroll
      for (int nf = 0; nf < 4; nf++) {
        bf16x8 kf = *(const bf16x8*)&Ks[buf][(nf * 16 + lr) * KVS + ks * 32 + lq * 8];
#pragma unroll
        for (int mf = 0; mf < 2; mf++)
          s[nf][mf] = __builtin_amdgcn_mfma_f32_16x16x32_bf16(kf, qf[mf][ks], s[nf][mf], 0, 0, 0);
      }
    // exp2 + packed P store: P[q][n] at pw[q*PS + 16B-chunk ^ swz(q)]
#pragma unroll
    for (int mf = 0; mf < 2; mf++)
#pragma unroll
      for (int nf = 0; nf < 4; nf++) {
        bf16x4 pk;
#pragma unroll
        for (int i = 0; i < 4; i++) pk[i] = (bf16_t)exp2f(s[nf][mf][i]);
        *(bf16x4*)&pw[(mf * 16 + lr) * PS + (((nf * 2 + (lq >> 1)) ^ swz) << 3) +
                      (lq & 1) * 4] = pk;
      }
    // PV, swapped: o[df][mf] = mfma(vf, pf) -> D[d][q]
#pragma unroll
    for (int ks = 0; ks < 2; ks++) {
      bf16x8 pf[2];
#pragma unroll
      for (int mf = 0; mf < 2; mf++)
        pf[mf] = *(const bf16x8*)&pw[(mf * 16 + lr) * PS + ((ks * 4 + (lq ^ swz)) << 3)];
#pragma unroll
      for (int df = 0; df < 4; df++) {
        bf16x8 vf = *(const bf16x8*)&Vs[buf][(df * 16 + lr) * KVS + ks * 32 + lq * 8];
#pragma unroll
        for (int mf = 0; mf < 2; mf++)
          o[df][mf] = __builtin_amdgcn_mfma_f32_16x16x32_bf16(vf, pf[mf], o[df][mf], 0, 0, 0);
      }
#pragma unroll
      for (int mf = 0; mf < 2; mf++)
        o5[mf] = __builtin_amdgcn_mfma_f32_16x16x32_bf16(onesA, pf[mf], o5[mf], 0, 0, 0);
    }
    if (it < 15) {
      *(bf16x8*)&Ks[buf ^ 1][sr * KVS + sc * 8] = nk0;
      *(bf16x8*)&Ks[buf ^ 1][(sr + 32) * KVS + sc * 8] = nk1;
      *(bf16x8*)&Vs[buf ^ 1][sr * KVS + sc * 8] = nv0;
      *(bf16x8*)&Vs[buf ^ 1][(sr + 32) * KVS + sc * 8] = nv1;
    }
    __syncthreads();
  }
  // epilogue: O[q][d] = o[df][mf][i] (rows d = df*16+lq*4+i, cols q = mf*16+lr)
#pragma unroll
  for (int mf = 0; mf < 2; mf++) {
    const float inv = 1.0f / o5[mf][0];  // lane-local rowsum for q = mf*16+lr
    const int grow = b * 1024 + q0 + mf * 16 + lr;
#pragma unroll
    for (int df = 0; df < 4; df++) {
      bf16x4 ov;
#pragma unroll
      for (int i = 0; i < 4; i++) ov[i] = (bf16_t)(o[df][mf][i] * inv);
      *(bf16x4*)&Ob[(size_t)grow * 1024 + h * 64 + df * 16 + lq * 4] = ov;
    }
  }
}

extern "C" void kernel_launch(void* const* d_in, const int* in_sizes, int n_in,
                              void* d_out, int out_size, void* d_ws, size_t ws_size,
                              hipStream_t stream) {
  const float* x     = (const float*)d_in[0];  // [8,1024,1024] f32
  const float* w_qkv = (const float*)d_in[1];  // [1024,3072] f32
  const float* w_out = (const float*)d_in[2];  // [1024,1024] f32
  const float* b_out = (const float*)d_in[3];  // [1024] f32
  float* out = (float*)d_out;                  // [8,1024,1024] f32

  bf16_t* ws = (bf16_t*)d_ws;
  const size_t SZ = (size_t)8 * 1024 * 1024;  // elems per 16MB buffer
  bf16_t* Qb  = ws;            // [B][H][N][64]  (pre-scaled)
  bf16_t* Kb  = Qb + SZ;       // [B][H][N][64]
  bf16_t* Vtb = Kb + SZ;       // [B][H][64][N]
  bf16_t* Ob  = Vtb + SZ;      // [B*N][H*64]; also aliases Xb (dead after gemm0)
  bf16_t* Wqt = Ob + SZ;       // [3072][1024]
  bf16_t* Wot = Wqt + (size_t)3072 * 1024;  // [1024][1024]
  bf16_t* Xb  = Ob;            // x as bf16 [8192][1024]
  // total ws use: 72 MB

  hipLaunchKernelGGL(convert_f32_bf16, dim3(4096), dim3(256), 0, stream, x, Xb);
  hipLaunchKernelGGL(transpose_f32_bf16, dim3(48, 16), dim3(64, 4), 0, stream,
                     w_qkv, Wqt, 1024, 3072);
  hipLaunchKernelGGL(transpose_f32_bf16, dim3(16, 16), dim3(64, 4), 0, stream,
                     w_out, Wot, 1024, 1024);
  hipLaunchKernelGGL((gemmT<0>), dim3(24, 64), dim3(256), 0, stream,
                     Xb, Wqt, Qb, Kb, Vtb, (const float*)nullptr, (float*)nullptr);
  hipLaunchKernelGGL(attn128, dim3(1024), dim3(256), 0, stream, Qb, Kb, Vtb, Ob);
  hipLaunchKernelGGL((gemmT<1>), dim3(8, 64), dim3(256), 0, stream,
                     Ob, Wot, (bf16_t*)nullptr, (bf16_t*)nullptr, (bf16_t*)nullptr,
                     b_out, out);
}

// Round 6
// 276.048 us; speedup vs baseline: 1.0273x; 1.0273x over previous
//
#include <hip/hip_runtime.h>
#include <hip/hip_bf16.h>
#include <math.h>

typedef __bf16 bf16_t;
typedef __bf16 bf16x4 __attribute__((ext_vector_type(4)));
typedef __bf16 bf16x8 __attribute__((ext_vector_type(8)));
typedef float f32x4 __attribute__((ext_vector_type(4)));

#define LOG2E 1.44269504088896340736f

// async global->LDS DMA, 16B per lane; LDS dest = wave-uniform base + lane*16
#define GL2LDS(g, l)                                                     \
  __builtin_amdgcn_global_load_lds(                                      \
      (const __attribute__((address_space(1))) unsigned int*)(g),        \
      (__attribute__((address_space(3))) unsigned int*)(l), 16, 0, 0)

// raw barrier with compiler memory fence (NO implicit vmcnt drain)
#define BAR() asm volatile("s_barrier" ::: "memory")
#define VMCNT(n) asm volatile("s_waitcnt vmcnt(" #n ")" ::: "memory")
#define LGKM0()                                         \
  do {                                                  \
    asm volatile("s_waitcnt lgkmcnt(0)" ::: "memory");  \
    __builtin_amdgcn_sched_barrier(0);                  \
  } while (0)

// ------------- convert f32 -> bf16, 8 elems/thread ------------------------
__global__ __launch_bounds__(256) void convert_f32_bf16(const float* __restrict__ in,
                                                        bf16_t* __restrict__ out) {
  const size_t idx = (size_t)(blockIdx.x * 256 + threadIdx.x) * 8;
  f32x4 a = *(const f32x4*)&in[idx];
  f32x4 b = *(const f32x4*)&in[idx + 4];
  bf16x8 v;
#pragma unroll
  for (int i = 0; i < 4; i++) { v[i] = (bf16_t)a[i]; v[i + 4] = (bf16_t)b[i]; }
  *(bf16x8*)&out[idx] = v;
}

// ------------- transpose+convert: in f32 [R][C] -> out bf16 [C][R] --------
__global__ __launch_bounds__(256) void transpose_f32_bf16(const float* __restrict__ in,
                                                          bf16_t* __restrict__ out,
                                                          int R, int C) {
  __shared__ bf16_t t[64][65];
  const int c0 = blockIdx.x * 64, r0 = blockIdx.y * 64;
  const int tx = threadIdx.x, ty = threadIdx.y;  // 64 x 4
#pragma unroll
  for (int i = 0; i < 16; i++) {
    int r = ty + i * 4;
    t[r][tx] = (bf16_t)in[(size_t)(r0 + r) * C + c0 + tx];
  }
  __syncthreads();
#pragma unroll
  for (int i = 0; i < 16; i++) {
    int r = ty + i * 4;
    out[(size_t)(c0 + r) * R + r0 + tx] = t[tx][r];
  }
}

// ---- 128x128 MFMA GEMM, BK=32, TRIPLE-buffered, counted vmcnt(4) ---------
// (round-4 best: 95 us gemm0, FETCH 57.6MB w/ XCD swizzle, 0 conflicts)
// Prefetch distance 2: at tile t stage tile t+2 into buf[(t+2)%3]; the
// end-of-tile VMCNT(4) waits only for group t+1 (issued one full tile ago)
// and leaves group t+2 in flight (T4). 256 thr = 4 waves (2x2), wave tile
// 64x64, LDS 48KB -> 3 blocks/CU.
// Swizzle (verified zero-conflict): LDS chunk (r,p) holds global chunk
// p ^ ((r>>1)&3); frag read at chunk lq ^ ((row>>1)&3) -> free 2-way.
// MODE 0: epilogue scatters qkv into Q(pre-scaled)/K [B][H][N][64], Vt [B][H][64][N]
// MODE 1: epilogue adds f32 bias, writes f32 [M][1024]
template <int MODE>
__global__ __launch_bounds__(256, 4) void gemmT(const bf16_t* __restrict__ A,
                                                const bf16_t* __restrict__ Bt,
                                                bf16_t* __restrict__ Qb,
                                                bf16_t* __restrict__ Kb,
                                                bf16_t* __restrict__ Vtb,
                                                const float* __restrict__ bias,
                                                float* __restrict__ Out) {
  constexpr int K = 1024;
  constexpr int NT = K / 32;  // 32 K-tiles
  __shared__ __align__(16) bf16_t As[3][128 * 32];
  __shared__ __align__(16) bf16_t Bs[3][128 * 32];
  // XCD-aware bijective swizzle (grid sizes are multiples of 8)
  const int gx = gridDim.x;
  const int lin = blockIdx.y * gx + blockIdx.x;
  const int per = (gx * gridDim.y) >> 3;
  const int swz = (lin & 7) * per + (lin >> 3);
  const int m0 = (swz / gx) * 128, n0 = (swz % gx) * 128;
  const int tid = threadIdx.x;
  const int w = tid >> 6, l = tid & 63;
  const int lr = l & 15, lq = l >> 4;
  const int wm = w >> 1, wn = w & 1;  // 2 x 2 wave grid, wave tile 64x64

  // staging: chunk c = slot*256 + tid; r = c>>2 = slot*64 + (tid>>2),
  // LDS pos p = c&3, source chunk = p ^ ((r>>1)&3) (slot-invariant)
  const int rs = tid >> 2, ps = tid & 3;
  const int cs = (ps ^ ((rs >> 1) & 3)) * 8;
  const size_t gA0 = (size_t)(m0 + rs) * K + cs;
  const size_t gA1 = (size_t)(m0 + 64 + rs) * K + cs;
  const size_t gB0 = (size_t)(n0 + rs) * K + cs;
  const size_t gB1 = (size_t)(n0 + 64 + rs) * K + cs;
  const int ldsu0 = (w * 64) * 8;          // wave-uniform LDS elem offsets
  const int ldsu1 = (256 + w * 64) * 8;

#define STG(bf_, kt_)                                   \
  do {                                                  \
    const size_t kk_ = (size_t)(kt_) * 32;              \
    GL2LDS(&A[gA0 + kk_], &As[bf_][ldsu0]);             \
    GL2LDS(&A[gA1 + kk_], &As[bf_][ldsu1]);             \
    GL2LDS(&Bt[gB0 + kk_], &Bs[bf_][ldsu0]);            \
    GL2LDS(&Bt[gB1 + kk_], &Bs[bf_][ldsu1]);            \
  } while (0)

  // frag ds_read offsets (elems); row*64B base + swizzled 16B chunk
  int aoff[4], boff[4];
#pragma unroll
  for (int mf = 0; mf < 4; mf++) {
    const int row = wm * 64 + mf * 16 + lr;
    aoff[mf] = row * 32 + ((lq ^ ((row >> 1) & 3)) << 3);
  }
#pragma unroll
  for (int nf = 0; nf < 4; nf++) {
    const int row = wn * 64 + nf * 16 + lr;
    boff[nf] = row * 32 + ((lq ^ ((row >> 1) & 3)) << 3);
  }

  f32x4 acc[4][4] = {};

  // prologue: stage tiles 0 and 1 (groups of 4 loads each); wait group 0
  STG(0, 0);
  STG(1, 1);
  VMCNT(4);
  BAR();

  for (int t = 0; t < NT; ++t) {
    const int bufR = t % 3;
    if (t + 2 < NT) STG((t + 2) % 3, t + 2);
    bf16x8 af[4], bv[4];
#pragma unroll
    for (int mf = 0; mf < 4; mf++)
      af[mf] = *(const bf16x8*)&As[bufR][aoff[mf]];
#pragma unroll
    for (int nf = 0; nf < 4; nf++)
      bv[nf] = *(const bf16x8*)&Bs[bufR][boff[nf]];
    LGKM0();
    __builtin_amdgcn_s_setprio(1);
#pragma unroll
    for (int mf = 0; mf < 4; mf++)
#pragma unroll
      for (int nf = 0; nf < 4; nf++)
        acc[mf][nf] = __builtin_amdgcn_mfma_f32_16x16x32_bf16(af[mf], bv[nf],
                                                              acc[mf][nf], 0, 0, 0);
    __builtin_amdgcn_s_setprio(0);
    // counted wait: group t+1 must land before the next tile reads it;
    // group t+2 (the 4 newest loads) stays in flight across the barrier.
    if (t == NT - 2) { VMCNT(0); } else if (t < NT - 2) { VMCNT(4); }
    BAR();
  }

#pragma unroll
  for (int mf = 0; mf < 4; mf++)
#pragma unroll
    for (int nf = 0; nf < 4; nf++)
#pragma unroll
      for (int i = 0; i < 4; i++) {
        const int m = m0 + wm * 64 + mf * 16 + lq * 4 + i;  // C/D row=(lane>>4)*4+i
        const int c = n0 + wn * 64 + nf * 16 + lr;          //     col=lane&15
        const float v = acc[mf][nf][i];
        if (MODE == 1) {
          Out[(size_t)m * 1024 + c] = v + bias[c];
        } else {
          const int b = m >> 10, n = m & 1023;
          const int which = c >> 10, cc = c & 1023;
          const int hh = cc >> 6, d = cc & 63;
          const size_t qk = ((size_t)((b * 16 + hh) * 1024 + n)) * 64 + d;
          if (which == 0)
            Qb[qk] = (bf16_t)(v * (0.125f * LOG2E));  // fold softmax scale+log2e
          else if (which == 1)
            Kb[qk] = (bf16_t)v;
          else
            Vtb[((size_t)((b * 16 + hh) * 64 + d)) * 1024 + n] = (bf16_t)v;
        }
      }
}

// ---------------- flash attention v5: DMA-staged K/V, swapped compute -----
// 1 block = (b, h, 128-query tile); 4 waves x 32 queries.
// Q pre-scaled by 0.125*log2e -> p = exp2(s).
// v5 change (theory: reg-staged K/V put 4 ds_write_b128 + lgkm drain on the
// critical path right before each barrier): K/V now staged by
// global_load_lds issued at ITER START into buf^1; writes land async under
// the MFMA/exp body; only vmcnt(0) (covering loads issued a full body
// earlier) remains before the barrier. Linear [64][64] LDS tiles with XOR
// chunk swizzle: LDS chunk (r,p) holds global chunk p ^ ((r>>1)&7); frag
// read chunk = (ks*4+lq) ^ ((lr>>1)&7) (row term vanishes mod 8) -> 64
// lanes spread 8 per 4-bank position = uniform, zero conflict.
// Swapped compute (v4): sT = mfma(kf,qf); P[q][n] packed b64 stores;
// o = mfma(vf,pf) -> O^T; rowsum via ones-A mfma (lane-local inv).
// setprio(1) wraps both MFMA clusters (measured +4-7% attn, m191).
#define PS  72
__global__ __launch_bounds__(256) void attn128(const bf16_t* __restrict__ Qb,
                                               const bf16_t* __restrict__ Kb,
                                               const bf16_t* __restrict__ Vtb,
                                               bf16_t* __restrict__ Ob) {
  __shared__ __align__(16) bf16_t Ks[2][64 * 64];
  __shared__ __align__(16) bf16_t Vs[2][64 * 64];
  __shared__ __align__(16) bf16_t Pl[4 * 32 * PS];
  const int bid = blockIdx.x;
  const int qt = bid >> 7, b = (bid >> 4) & 7, h = bid & 15;
  const bf16_t* Qh = Qb + (size_t)((b * 16 + h) * 1024) * 64;
  const bf16_t* Kh = Kb + (size_t)((b * 16 + h) * 1024) * 64;
  const bf16_t* Vh = Vtb + (size_t)((b * 16 + h) * 64) * 1024;  // [64][1024] = V^T
  const int tid = threadIdx.x, w = tid >> 6, l = tid & 63;
  const int lr = l & 15, lq = l >> 4;
  const int q0 = qt * 128 + w * 32;
  const int swz = (lr >> 1) & 3;
  const int g7 = (lr >> 1) & 7;
  const int kc0 = (lq ^ g7) * 8;        // K/V read chunk, ks=0
  const int kc1 = ((4 + lq) ^ g7) * 8;  // ks=1

  bf16x8 onesA;
#pragma unroll
  for (int i = 0; i < 8; i++) onesA[i] = (bf16_t)1.0f;

  // staging: chunk c = slot*256 + tid; r = c>>3, LDS pos p = tid&7,
  // source chunk = p ^ ((r>>1)&7); LDS dest linear (wave-uniform + lane*16B)
  const int r0 = tid >> 3, r1 = r0 + 32, p0 = tid & 7;
  const int ck0 = (p0 ^ ((r0 >> 1) & 7)) * 8;
  const int ck1 = (p0 ^ ((r1 >> 1) & 7)) * 8;
  const int ldsS0 = (w * 64) * 8;
  const int ldsS1 = (256 + w * 64) * 8;

#define STGKV(bf_, j_)                                                  \
  do {                                                                  \
    const size_t jb = (size_t)(j_) * 64;                                \
    GL2LDS(&Kh[(jb + r0) * 64 + ck0], &Ks[bf_][ldsS0]);                 \
    GL2LDS(&Kh[(jb + r1) * 64 + ck1], &Ks[bf_][ldsS1]);                 \
    GL2LDS(&Vh[(size_t)r0 * 1024 + jb + ck0], &Vs[bf_][ldsS0]);         \
    GL2LDS(&Vh[(size_t)r1 * 1024 + jb + ck1], &Vs[bf_][ldsS1]);         \
  } while (0)

  bf16x8 qf[2][2];
#pragma unroll
  for (int mf = 0; mf < 2; mf++)
#pragma unroll
    for (int ks = 0; ks < 2; ks++)
      qf[mf][ks] = *(const bf16x8*)&Qh[(size_t)(q0 + mf * 16 + lr) * 64 + ks * 32 + lq * 8];

  STGKV(0, 0);
  VMCNT(0);
  BAR();

  f32x4 o[4][2] = {};   // [df][mf] O^T frags: rows d, cols q
  f32x4 o5[2] = {};     // rowsum(q) per mf (all regs identical)
  bf16_t* pw = &Pl[w * 32 * PS];

  for (int it = 0; it < 16; ++it) {
    const int buf = it & 1;
    if (it < 15) STGKV(buf ^ 1, it + 1);
    // QK^T, swapped: sT[nf][mf] rows n = nf*16+lq*4+i, cols q = mf*16+lr
    f32x4 s[4][2] = {};
    __builtin_amdgcn_s_setprio(1);
#pragma unroll
    for (int ks = 0; ks < 2; ks++)
#pragma unroll
      for (int nf = 0; nf < 4; nf++) {
        bf16x8 kf = *(const bf16x8*)&Ks[buf][(nf * 16 + lr) * 64 + (ks ? kc1 : kc0)];
#pragma unroll
        for (int mf = 0; mf < 2; mf++)
          s[nf][mf] = __builtin_amdgcn_mfma_f32_16x16x32_bf16(kf, qf[mf][ks], s[nf][mf], 0, 0, 0);
      }
    __builtin_amdgcn_s_setprio(0);
    // exp2 + packed P store: P[q][n] at pw[q*PS + 16B-chunk ^ swz(q)]
#pragma unroll
    for (int mf = 0; mf < 2; mf++)
#pragma unroll
      for (int nf = 0; nf < 4; nf++) {
        bf16x4 pk;
#pragma unroll
        for (int i = 0; i < 4; i++) pk[i] = (bf16_t)exp2f(s[nf][mf][i]);
        *(bf16x4*)&pw[(mf * 16 + lr) * PS + (((nf * 2 + (lq >> 1)) ^ swz) << 3) +
                      (lq & 1) * 4] = pk;
      }
    // PV, swapped: o[df][mf] = mfma(vf, pf) -> D[d][q]
    __builtin_amdgcn_s_setprio(1);
#pragma unroll
    for (int ks = 0; ks < 2; ks++) {
      bf16x8 pf[2];
#pragma unroll
      for (int mf = 0; mf < 2; mf++)
        pf[mf] = *(const bf16x8*)&pw[(mf * 16 + lr) * PS + ((ks * 4 + (lq ^ swz)) << 3)];
#pragma unroll
      for (int df = 0; df < 4; df++) {
        bf16x8 vf = *(const bf16x8*)&Vs[buf][(df * 16 + lr) * 64 + (ks ? kc1 : kc0)];
#pragma unroll
        for (int mf = 0; mf < 2; mf++)
          o[df][mf] = __builtin_amdgcn_mfma_f32_16x16x32_bf16(vf, pf[mf], o[df][mf], 0, 0, 0);
      }
#pragma unroll
      for (int mf = 0; mf < 2; mf++)
        o5[mf] = __builtin_amdgcn_mfma_f32_16x16x32_bf16(onesA, pf[mf], o5[mf], 0, 0, 0);
    }
    __builtin_amdgcn_s_setprio(0);
    VMCNT(0);
    BAR();
  }
  // epilogue: O[q][d] = o[df][mf][i] (rows d = df*16+lq*4+i, cols q = mf*16+lr)
#pragma unroll
  for (int mf = 0; mf < 2; mf++) {
    const float inv = 1.0f / o5[mf][0];  // lane-local rowsum for q = mf*16+lr
    const int grow = b * 1024 + q0 + mf * 16 + lr;
#pragma unroll
    for (int df = 0; df < 4; df++) {
      bf16x4 ov;
#pragma unroll
      for (int i = 0; i < 4; i++) ov[i] = (bf16_t)(o[df][mf][i] * inv);
      *(bf16x4*)&Ob[(size_t)grow * 1024 + h * 64 + df * 16 + lq * 4] = ov;
    }
  }
}

extern "C" void kernel_launch(void* const* d_in, const int* in_sizes, int n_in,
                              void* d_out, int out_size, void* d_ws, size_t ws_size,
                              hipStream_t stream) {
  const float* x     = (const float*)d_in[0];  // [8,1024,1024] f32
  const float* w_qkv = (const float*)d_in[1];  // [1024,3072] f32
  const float* w_out = (const float*)d_in[2];  // [1024,1024] f32
  const float* b_out = (const float*)d_in[3];  // [1024] f32
  float* out = (float*)d_out;                  // [8,1024,1024] f32

  bf16_t* ws = (bf16_t*)d_ws;
  const size_t SZ = (size_t)8 * 1024 * 1024;  // elems per 16MB buffer
  bf16_t* Qb  = ws;            // [B][H][N][64]  (pre-scaled)
  bf16_t* Kb  = Qb + SZ;       // [B][H][N][64]
  bf16_t* Vtb = Kb + SZ;       // [B][H][64][N]
  bf16_t* Ob  = Vtb + SZ;      // [B*N][H*64]; also aliases Xb (dead after gemm0)
  bf16_t* Wqt = Ob + SZ;       // [3072][1024]
  bf16_t* Wot = Wqt + (size_t)3072 * 1024;  // [1024][1024]
  bf16_t* Xb  = Ob;            // x as bf16 [8192][1024]
  // total ws use: 72 MB

  hipLaunchKernelGGL(convert_f32_bf16, dim3(4096), dim3(256), 0, stream, x, Xb);
  hipLaunchKernelGGL(transpose_f32_bf16, dim3(48, 16), dim3(64, 4), 0, stream,
                     w_qkv, Wqt, 1024, 3072);
  hipLaunchKernelGGL(transpose_f32_bf16, dim3(16, 16), dim3(64, 4), 0, stream,
                     w_out, Wot, 1024, 1024);
  hipLaunchKernelGGL((gemmT<0>), dim3(24, 64), dim3(256), 0, stream,
                     Xb, Wqt, Qb, Kb, Vtb, (const float*)nullptr, (float*)nullptr);
  hipLaunchKernelGGL(attn128, dim3(1024), dim3(256), 0, stream, Qb, Kb, Vtb, Ob);
  hipLaunchKernelGGL((gemmT<1>), dim3(8, 64), dim3(256), 0, stream,
                     Ob, Wot, (bf16_t*)nullptr, (bf16_t*)nullptr, (bf16_t*)nullptr,
                     b_out, out);
}